// Round 6
// baseline (281.248 us; speedup 1.0000x reference)
//
#include <hip/hip_runtime.h>
#include <stdint.h>

// Problem dims (fixed by reference)
#define M_ROWS 8192
#define K_DIM  4096
#define NCOLS  128     // fused layer-1 cols: [0,64)=C branch, [64,128)=R branch
#define OUTD   144     // per-branch flat size (78 real + 66 imag)
#define PLANE  1179648 // complex elements per output (8192*144)

typedef __attribute__((ext_vector_type(4))) float  float4v;
typedef __attribute__((ext_vector_type(8))) short  short8v;
typedef __attribute__((ext_vector_type(4))) short  short4v;

static __device__ __forceinline__ unsigned short f2bf(float f) {
    // round-to-nearest-even fp32 -> bf16
    unsigned int u = __builtin_bit_cast(unsigned int, f);
    u += 0x7FFFu + ((u >> 16) & 1u);
    return (unsigned short)(u >> 16);
}

// ---------------------------------------------------------------------------
// Prep: Wt[n][k] = W1[k][n] as bf16, n in [0,128) = [WC1 cols | WR1 cols]
// ---------------------------------------------------------------------------
__global__ __launch_bounds__(256) void wt_kernel(
    const float* __restrict__ WC1, const float* __restrict__ WR1,
    unsigned short* __restrict__ Wt) {
    __shared__ float tile[64][65];
    const float* src = (blockIdx.y == 0) ? WC1 : WR1;
    const int k0 = blockIdx.x * 64;
    const int t = threadIdx.x;
    const int j = t & 63, q = t >> 6;
#pragma unroll
    for (int p = 0; p < 16; ++p) {
        int i = p * 4 + q;
        tile[i][j] = src[(size_t)(k0 + i) * 64 + j];
    }
    __syncthreads();
#pragma unroll
    for (int p = 0; p < 16; ++p) {
        int n = p * 4 + q;
        Wt[(size_t)(blockIdx.y * 64 + n) * K_DIM + k0 + j] = f2bf(tile[j][n]);
    }
}

// ---------------------------------------------------------------------------
// Fused: per 16-row tile, GEMM1 (bf16 MFMA) -> layer2 -> layer3 -> Cholesky
// outer product, all through one aliased LDS region. Output bf16,
// IM-FIRST INTERLEAVED: flat[2q] = Im, flat[2q+1] = Re, q = b*144 + i*12 + j;
// C block at [0, 2*PLANE), R block at [2*PLANE, 4*PLANE).
// ---------------------------------------------------------------------------
__global__ __launch_bounds__(256) void fused_kernel(
    const float* __restrict__ X, const unsigned short* __restrict__ Wt,
    const float* __restrict__ bC1, const float* __restrict__ bR1,
    const float* __restrict__ WC2, const float* __restrict__ bC2,
    const float* __restrict__ WR2, const float* __restrict__ bR2,
    const float* __restrict__ WC3, const float* __restrict__ bC3,
    const float* __restrict__ WR3, const float* __restrict__ bR3,
    unsigned short* __restrict__ OUT) {
    // LDS union:
    //  phase1: Asm [16][72] u16 (2304 B) | Bsm [128][72] u16 (18432 B)
    //  phase2: hs  [16][132] f32 (8448 B) | W2s [64][128] f32 (32768 B)
    //  phase3+: fl [16][288] f32 (18432 B) overlays W2s
    __shared__ __align__(16) char smem[41216];
    unsigned short* Asm_ = (unsigned short*)smem;          // [16][72]
    unsigned short* Bsm_ = Asm_ + 16 * 72;                 // [128][72]
    float* hs  = (float*)smem;                             // [16][132]
    float* W2s = hs + 16 * 132;                            // [64][128]
    float* fl  = W2s;                                      // [16][288]

    const int tid  = threadIdx.x;
    const int lane = tid & 63;
    const int w    = tid >> 6;          // wave 0..3 -> col tiles [32w, 32w+32)
    const int r0   = blockIdx.x * 16;
    const int m    = lane & 15, q = lane >> 4;
    const int ar   = tid >> 4, akc = tid & 15;  // A staging: row, k-chunk/4

    float4v acc0 = {0.f, 0.f, 0.f, 0.f};
    float4v acc1 = {0.f, 0.f, 0.f, 0.f};

    // ---------------- Phase 1: GEMM1 (16 x 4096 @ 4096 x 128, bf16 MFMA) ----
    for (int kk = 0; kk < K_DIM; kk += 64) {
        float4 x = *(const float4*)(X + (size_t)(r0 + ar) * K_DIM + kk + akc * 4);
        short4v s;
        s.x = (short)f2bf(x.x); s.y = (short)f2bf(x.y);
        s.z = (short)f2bf(x.z); s.w = (short)f2bf(x.w);
        uint4 breg[4];
#pragma unroll
        for (int p = 0; p < 4; ++p) {
            int ci = p * 256 + tid;
            int n = ci >> 3, k8 = ci & 7;
            breg[p] = *(const uint4*)(Wt + (size_t)n * K_DIM + kk + k8 * 8);
        }
        *(short4v*)&Asm_[ar * 72 + akc * 4] = s;
#pragma unroll
        for (int p = 0; p < 4; ++p) {
            int ci = p * 256 + tid;
            int n = ci >> 3, k8 = ci & 7;
            *(uint4*)&Bsm_[n * 72 + k8 * 8] = breg[p];
        }
        __syncthreads();
#pragma unroll
        for (int ks = 0; ks < 2; ++ks) {
            short8v a  = *(const short8v*)&Asm_[m * 72 + ks * 32 + q * 8];
            short8v b0 = *(const short8v*)&Bsm_[(w * 32 + m) * 72 + ks * 32 + q * 8];
            short8v b1 = *(const short8v*)&Bsm_[(w * 32 + 16 + m) * 72 + ks * 32 + q * 8];
            acc0 = __builtin_amdgcn_mfma_f32_16x16x32_bf16(a, b0, acc0, 0, 0, 0);
            acc1 = __builtin_amdgcn_mfma_f32_16x16x32_bf16(a, b1, acc1, 0, 0, 0);
        }
        __syncthreads();
    }
    // Epilogue: C/D layout col=lane&15, row=quad*4+reg. Write h1 into hs.
    {
        const int c0 = w * 32 + m;
        const int c1 = w * 32 + 16 + m;
        const float bv0 = (c0 < 64) ? bC1[c0] : bR1[c0 - 64];
        const float bv1 = (c1 < 64) ? bC1[c1] : bR1[c1 - 64];
#pragma unroll
        for (int i = 0; i < 4; ++i) {
            int r = q * 4 + i;
            float v0 = acc0[i] + bv0; v0 = v0 > 0.f ? v0 : 0.f;
            float v1 = acc1[i] + bv1; v1 = v1 > 0.f ? v1 : 0.f;
            hs[r * 132 + c0] = v0;
            hs[r * 132 + c1] = v1;
        }
    }
    // Stage W2 = [WC2 | WR2] into LDS (64 x 128 f32).
#pragma unroll
    for (int p = 0; p < 8; ++p) {    // 2048 float4
        int fi = p * 256 + tid;
        int k = fi >> 5, c4 = fi & 31;
        int c = c4 * 4;
        const float* wsrc = (c < 64) ? (WC2 + (size_t)k * 64 + c)
                                     : (WR2 + (size_t)k * 64 + (c - 64));
        *(float4*)&W2s[k * 128 + c] = *(const float4*)wsrc;
    }
    __syncthreads();

    // ---------------- Phase 2: layer 2 (h2 = relu(h1 @ W2 + b2)) -----------
    const int rg = tid >> 5;          // 8 row-groups x 2 rows
    const int cg = tid & 31;          // 32 col quads
    const int koff2 = (cg < 16) ? 0 : 64;
    float acc2[2][4];
    {
        int c = cg * 4;
        const float* bsrc = (c < 64) ? (bC2 + c) : (bR2 + (c - 64));
#pragma unroll
        for (int i = 0; i < 2; ++i)
#pragma unroll
            for (int j = 0; j < 4; ++j) acc2[i][j] = bsrc[j];
    }
    for (int k = 0; k < 64; ++k) {
        float4 wv = *(const float4*)&W2s[k * 128 + cg * 4];
#pragma unroll
        for (int i = 0; i < 2; ++i) {
            float a = hs[(rg * 2 + i) * 132 + koff2 + k];
            acc2[i][0] += a * wv.x; acc2[i][1] += a * wv.y;
            acc2[i][2] += a * wv.z; acc2[i][3] += a * wv.w;
        }
    }
    float h2r[2][4];
#pragma unroll
    for (int i = 0; i < 2; ++i)
#pragma unroll
        for (int j = 0; j < 4; ++j)
            h2r[i][j] = acc2[i][j] > 0.f ? acc2[i][j] : 0.f;
    __syncthreads();                   // all reads of hs(h1)/W2s done
#pragma unroll
    for (int i = 0; i < 2; ++i) {
        float4 v; v.x = h2r[i][0]; v.y = h2r[i][1]; v.z = h2r[i][2]; v.w = h2r[i][3];
        *(float4*)&hs[(rg * 2 + i) * 132 + cg * 4] = v;   // hs now holds h2
    }
    __syncthreads();

    // ---------------- Phase 3: layer 3 -> fl[16][288] (overlays W2s) -------
    for (int pass = 0; pass < 3; ++pass) {
        int c = pass * 128 + cg * 4;
        if (c < 288) {
            const int brn = (c >= 144);
            const int cl = c - (brn ? 144 : 0);
            const float* W3 = brn ? WR3 : WC3;
            const float* b3 = brn ? bR3 : bC3;
            const int ko = brn ? 64 : 0;
            float a3[2][4];
#pragma unroll
            for (int i = 0; i < 2; ++i)
#pragma unroll
                for (int j = 0; j < 4; ++j) a3[i][j] = b3[cl + j];
            for (int k = 0; k < 64; ++k) {
                float4 wv = *(const float4*)(W3 + (size_t)k * OUTD + cl);
#pragma unroll
                for (int i = 0; i < 2; ++i) {
                    float a = hs[(rg * 2 + i) * 132 + ko + k];
                    a3[i][0] += a * wv.x; a3[i][1] += a * wv.y;
                    a3[i][2] += a * wv.z; a3[i][3] += a * wv.w;
                }
            }
#pragma unroll
            for (int i = 0; i < 2; ++i) {
                float4 v; v.x = a3[i][0]; v.y = a3[i][1]; v.z = a3[i][2]; v.w = a3[i][3];
                *(float4*)&fl[(rg * 2 + i) * 288 + c] = v;
            }
        }
    }
    __syncthreads();

    // ---------------- Phase 4: softplus on the 12 diag reals per (row,brn) -
#pragma unroll
    for (int p = 0; p < 2; ++p) {
        int idx = p * 256 + tid;
        if (idx < 384) {
            int r = idx / 24, rem = idx % 24;
            int brn = rem / 12, ii = rem % 12;
            float* f = &fl[r * 288 + brn * 144];
            int d = ii * (ii + 1) / 2 + ii;
            float xv = f[d];
            f[d] = (xv > 20.f) ? xv : log1pf(expf(xv));
        }
    }
    __syncthreads();

    // ---------------- Phase 5: C = L L^H, Hermitian mirror, write OUT ------
    // IM-FIRST interleaved: OUT[base + 2q] = Im, OUT[base + 2q + 1] = Re;
    // q = (r0+r)*144 + i*12 + j; base = brn ? 2*PLANE*... (R block) : 0.
    for (int task = tid; task < 16 * 2 * 78; task += 256) {
        int r = task / 156, rem = task % 156;
        int brn = rem / 78, p = rem % 78;
        int i = 0;
        while (p >= (i + 1) * (i + 2) / 2) ++i;
        int j = p - i * (i + 1) / 2;              // j <= i
        const float* f = &fl[r * 288 + brn * 144]; // reals (diag softplus'd)
        const float* g = f + 78;                   // strict-lower imags
        const int ti = i * (i + 1) / 2, tj = j * (j + 1) / 2;
        const int si = i * (i - 1) / 2, sj = j * (j - 1) / 2;
        float re = 0.f, im = 0.f;
        for (int k = 0; k <= j; ++k) {
            float ar_ = f[ti + k];
            float ai  = (k == i) ? 0.f : g[si + k];
            float br_ = f[tj + k];
            float bi  = (k == j) ? 0.f : g[sj + k];
            re += ar_ * br_ + ai * bi;             // Re(L[i] . conj(L[j]))
            im += ai * br_ - ar_ * bi;             // Im
        }
        unsigned short reb = f2bf(re);
        unsigned short imb = f2bf(im);
        unsigned short imn = f2bf(-im);
        size_t base = brn ? (size_t)(2 * PLANE) : 0;
        size_t q1 = (size_t)(r0 + r) * 144 + (size_t)(i * 12 + j);
        OUT[base + 2 * q1]     = imb;   // imag first
        OUT[base + 2 * q1 + 1] = reb;   // then real
        if (i != j) {
            size_t q2 = (size_t)(r0 + r) * 144 + (size_t)(j * 12 + i);
            OUT[base + 2 * q2]     = imn;
            OUT[base + 2 * q2 + 1] = reb;
        }
    }
}

// ---------------------------------------------------------------------------
extern "C" void kernel_launch(void* const* d_in, const int* in_sizes, int n_in,
                              void* d_out, int out_size, void* d_ws, size_t ws_size,
                              hipStream_t stream) {
    const float* X   = (const float*)d_in[0];
    const float* WC1 = (const float*)d_in[1];
    const float* bC1 = (const float*)d_in[2];
    const float* WC2 = (const float*)d_in[3];
    const float* bC2 = (const float*)d_in[4];
    const float* WC3 = (const float*)d_in[5];
    const float* bC3 = (const float*)d_in[6];
    const float* WR1 = (const float*)d_in[7];
    const float* bR1 = (const float*)d_in[8];
    const float* WR2 = (const float*)d_in[9];
    const float* bR2 = (const float*)d_in[10];
    const float* WR3 = (const float*)d_in[11];
    const float* bR3 = (const float*)d_in[12];

    unsigned short* Wt = (unsigned short*)d_ws;   // 128 x 4096 bf16 = 1 MB
    unsigned short* OUT = (unsigned short*)d_out; // bf16, im-first interleaved

    wt_kernel<<<dim3(64, 2), 256, 0, stream>>>(WC1, WR1, Wt);
    fused_kernel<<<M_ROWS / 16, 256, 0, stream>>>(
        X, Wt, bC1, bR1, WC2, bC2, WR2, bR2, WC3, bC3, WR3, bR3, OUT);
}